// Round 1
// baseline (92.172 us; speedup 1.0000x reference)
//
#include <hip/hip_runtime.h>
#include <hip/hip_bf16.h>
#include <stdint.h>

#define D     256
#define NTOT  8192
#define NSRC  4096

using bf16x8 = __attribute__((ext_vector_type(8))) short;
using f32x4  = __attribute__((ext_vector_type(4))) float;

#define GLB_AS __attribute__((address_space(1)))
#define LDS_AS __attribute__((address_space(3)))

#if __has_builtin(__builtin_amdgcn_exp2f)
#define EXP2F __builtin_amdgcn_exp2f
#else
#define EXP2F exp2f
#endif

// workspace layout (bytes)
#define OFF_XB   ((size_t)0)
#define OFF_SQ   ((size_t)NTOT * D * 2)          // 4 MB of bf16 X
#define OFF_COL  (OFF_SQ + (size_t)NTOT * 4)     // row sq-norms (f32)
#define OFF_CO   (OFF_COL + 256 * 4)             // column sums (f32)
#define OFF_ACC  (OFF_CO + 32)                   // 5 coeffs (f32, padded)
#define OFF_END  (OFF_ACC + 32)                  // 3 doubles (+pad)

// ---------------- prep: f32 -> bf16, row sq-norms, column sums ----------------
__global__ __launch_bounds__(256) void prep_kernel(
    const float* __restrict__ src, const float* __restrict__ tgt,
    __hip_bfloat16* __restrict__ xb, float* __restrict__ sq,
    float* __restrict__ colsum)
{
  __shared__ float scol[256];
  const int tid = threadIdx.x;
  scol[tid] = 0.f;
  __syncthreads();
  const int wave = tid >> 6, lane = tid & 63;
  const int rowbase = blockIdx.x * 32 + wave * 8;
  for (int rr = 0; rr < 8; ++rr) {
    const int row = rowbase + rr;
    const float* p = (row < NSRC) ? (src + (size_t)row * D)
                                  : (tgt + (size_t)(row - NSRC) * D);
    float sqacc = 0.f;
    #pragma unroll
    for (int c = 0; c < 4; ++c) {
      const int col = lane + 64 * c;
      const float v = p[col];
      const __hip_bfloat16 b = __float2bfloat16(v);
      xb[(size_t)row * D + col] = b;
      const float vb = __bfloat162float(b);
      sqacc += vb * vb;
      atomicAdd(&scol[col], vb);
    }
    #pragma unroll
    for (int off = 32; off > 0; off >>= 1) sqacc += __shfl_down(sqacc, off);
    if (lane == 0) sq[row] = sqacc;
  }
  __syncthreads();
  atomicAdd(&colsum[tid], scol[tid]);
}

// ---------------- bandwidth via sum(d2) = 2N*S - 2*||s||^2 ----------------
__global__ __launch_bounds__(256) void bw_kernel(
    const float* __restrict__ sq, const float* __restrict__ colsum,
    float* __restrict__ coeffs)
{
  __shared__ float red[256];
  const int t = threadIdx.x;
  float s = 0.f;
  for (int k = t; k < NTOT; k += 256) s += sq[k];
  red[t] = s;
  __syncthreads();
  for (int off = 128; off > 0; off >>= 1) {
    if (t < off) red[t] += red[t + off];
    __syncthreads();
  }
  const float S = red[0];
  __syncthreads();
  const float cv = colsum[t];
  red[t] = cv * cv;
  __syncthreads();
  for (int off = 128; off > 0; off >>= 1) {
    if (t < off) red[t] += red[t + off];
    __syncthreads();
  }
  if (t == 0) {
    const double sumd2 = 2.0 * (double)NTOT * (double)S - 2.0 * (double)red[0];
    const double bw = sumd2 / ((double)NTOT * (double)NTOT - (double)NTOT) / 4.0;
    #pragma unroll
    for (int i = 0; i < 5; ++i)
      coeffs[i] = (float)(-1.4426950408889634 / (bw * (double)(1 << i)));
  }
}

// ---------------- main: 128x128 pair tiles, bf16 MFMA + fused exp epilogue ----------------
__global__ __launch_bounds__(256) void pair_kernel(
    const __hip_bfloat16* __restrict__ xb, const float* __restrict__ sq,
    const float* __restrict__ coeffs, double* __restrict__ accum)
{
  const int bj = blockIdx.x, bi = blockIdx.y;
  if (bj < bi) return;  // symmetry: only upper-triangular tiles

  __shared__ __align__(16) short lA[128 * 64];
  __shared__ __align__(16) short lB[128 * 64];
  __shared__ float sqA[128], sqB[128], wsum[4];

  const int tid = threadIdx.x;
  const int wave = tid >> 6, lane = tid & 63;
  const int wr = wave >> 1, wc = wave & 1;

  if (tid < 128) sqA[tid] = sq[bi * 128 + tid];
  else           sqB[tid - 128] = sq[bj * 128 + (tid - 128)];

  const float c0 = coeffs[0], c1 = coeffs[1], c2 = coeffs[2],
              c3 = coeffs[3], c4 = coeffs[4];

  f32x4 acc[4][4];
  #pragma unroll
  for (int mi = 0; mi < 4; ++mi)
    #pragma unroll
    for (int nj = 0; nj < 4; ++nj)
      acc[mi][nj] = (f32x4){0.f, 0.f, 0.f, 0.f};

  // Staging: global_load_lds writes linear (wave-uniform base + lane*16).
  // LDS[row][b] must hold G[row][b ^ ((row&7)<<4)] (st-swizzle), so the
  // per-lane GLOBAL source column is pre-swizzled (rule 21: inverse-swz source
  // + swz read; XOR is its own inverse).
  const int srow = lane >> 3;                       // row within 8-row wave chunk
  const int scol_e = (((lane & 7) ^ (lane >> 3)) ) * 8;  // swizzled elem offset
  const __hip_bfloat16* gA = xb + (size_t)(bi * 128 + wave * 8 + srow) * D + scol_e;
  const __hip_bfloat16* gB = xb + (size_t)(bj * 128 + wave * 8 + srow) * D + scol_e;
  char* ldsA = (char*)lA + (wave * 8) * 128;
  char* ldsB = (char*)lB + (wave * 8) * 128;

  for (int kk = 0; kk < D; kk += 64) {
    __syncthreads();  // previous iter's ds_reads done before overwrite
    #pragma unroll
    for (int q = 0; q < 4; ++q) {
      __builtin_amdgcn_global_load_lds(
          (const GLB_AS uint32_t*)(gA + (size_t)q * 32 * D + kk),
          (LDS_AS uint32_t*)(ldsA + q * 32 * 128), 16, 0, 0);
      __builtin_amdgcn_global_load_lds(
          (const GLB_AS uint32_t*)(gB + (size_t)q * 32 * D + kk),
          (LDS_AS uint32_t*)(ldsB + q * 32 * 128), 16, 0, 0);
    }
    __syncthreads();  // compiler drains vmcnt(0) before barrier

    #pragma unroll
    for (int ks = 0; ks < 2; ++ks) {
      bf16x8 af[4], bfr[4];
      const int kb = (ks * 32 + (lane >> 4) * 8) * 2;  // byte offset within row
      #pragma unroll
      for (int mi = 0; mi < 4; ++mi) {
        const int row = wr * 64 + mi * 16 + (lane & 15);
        af[mi] = *(const bf16x8*)((const char*)lA + row * 128 + (kb ^ ((row & 7) << 4)));
      }
      #pragma unroll
      for (int nj = 0; nj < 4; ++nj) {
        const int row = wc * 64 + nj * 16 + (lane & 15);
        bfr[nj] = *(const bf16x8*)((const char*)lB + row * 128 + (kb ^ ((row & 7) << 4)));
      }
      #pragma unroll
      for (int mi = 0; mi < 4; ++mi)
        #pragma unroll
        for (int nj = 0; nj < 4; ++nj)
          acc[mi][nj] = __builtin_amdgcn_mfma_f32_16x16x32_bf16(
              af[mi], bfr[nj], acc[mi][nj], 0, 0, 0);
    }
  }

  // epilogue: d2 = sq_i + sq_j - 2*gram; k = sum_t exp2(d2 * c_t)
  float tsum = 0.f;
  const int r0 = (lane >> 4) * 4;  // C/D layout: row=(lane>>4)*4+reg, col=lane&15
  const int cc = lane & 15;
  #pragma unroll
  for (int mi = 0; mi < 4; ++mi) {
    #pragma unroll
    for (int r = 0; r < 4; ++r) {
      const float si = sqA[wr * 64 + mi * 16 + r0 + r];
      #pragma unroll
      for (int nj = 0; nj < 4; ++nj) {
        const float sj = sqB[wc * 64 + nj * 16 + cc];
        float d2 = fmaf(-2.f, acc[mi][nj][r], si + sj);
        d2 = fmaxf(d2, 0.f);
        tsum += EXP2F(d2 * c0) + EXP2F(d2 * c1) + EXP2F(d2 * c2)
              + EXP2F(d2 * c3) + EXP2F(d2 * c4);
      }
    }
  }
  #pragma unroll
  for (int off = 32; off > 0; off >>= 1) tsum += __shfl_down(tsum, off);
  if (lane == 0) wsum[wave] = tsum;
  __syncthreads();
  if (tid == 0) {
    const float bsum = wsum[0] + wsum[1] + wsum[2] + wsum[3];
    // categories: 0=XX (bi,bj<32), 1=YY (bi>=32), 2=XY (bi<32<=bj)
    const int cat = (bi >= 32) ? 1 : ((bj >= 32) ? 2 : 0);
    const double w = (bi == bj) ? 1.0 : 2.0;  // off-diag tile covers mirror too
    atomicAdd(&accum[cat], w * (double)bsum);
  }
}

__global__ void out_kernel(const double* __restrict__ accum, float* __restrict__ out)
{
  if (threadIdx.x == 0)
    out[0] = (float)((accum[0] + accum[1] - accum[2]) /
                     ((double)NSRC * (double)NSRC));
}

extern "C" void kernel_launch(void* const* d_in, const int* in_sizes, int n_in,
                              void* d_out, int out_size, void* d_ws, size_t ws_size,
                              hipStream_t stream) {
  (void)in_sizes; (void)n_in; (void)out_size; (void)ws_size;
  const float* src = (const float*)d_in[0];
  const float* tgt = (const float*)d_in[1];
  char* ws = (char*)d_ws;
  __hip_bfloat16* xb = (__hip_bfloat16*)(ws + OFF_XB);
  float* sq     = (float*)(ws + OFF_SQ);
  float* colsum = (float*)(ws + OFF_COL);
  float* coeffs = (float*)(ws + OFF_CO);
  double* accum = (double*)(ws + OFF_ACC);

  hipMemsetAsync(ws + OFF_COL, 0, OFF_END - OFF_COL, stream);
  prep_kernel<<<256, 256, 0, stream>>>(src, tgt, xb, sq, colsum);
  bw_kernel<<<1, 256, 0, stream>>>(sq, colsum, coeffs);
  dim3 grid(64, 64);
  pair_kernel<<<grid, 256, 0, stream>>>(xb, sq, coeffs, accum);
  out_kernel<<<1, 64, 0, stream>>>(accum, (float*)d_out);
}

// Round 2
// 88.167 us; speedup vs baseline: 1.0454x; 1.0454x over previous
//
#include <hip/hip_runtime.h>
#include <hip/hip_bf16.h>
#include <stdint.h>
#include <math.h>

#define D     256
#define NTOT  8192
#define NSRC  4096
#define NT    64                  // 64 row/col tiles of 128
#define NTRI  (NT * (NT + 1) / 2) // 2080 upper-tri tiles

using bf16x8 = __attribute__((ext_vector_type(8))) short;
using f32x4  = __attribute__((ext_vector_type(4))) float;

#define GLB_AS __attribute__((address_space(1)))
#define LDS_AS __attribute__((address_space(3)))

#if __has_builtin(__builtin_amdgcn_exp2f)
#define EXP2F __builtin_amdgcn_exp2f
#else
#define EXP2F exp2f
#endif

// workspace layout (bytes)
#define OFF_XB   ((size_t)0)                     // 4 MB bf16 X
#define OFF_SQ   ((size_t)NTOT * D * 2)          // 8192 f32 row sq-norms
#define OFF_COL  (OFF_SQ + (size_t)NTOT * 4)     // 256 f32 column sums
#define OFF_SS   (OFF_COL + 256 * 4)             // f32 sum of sq-norms
#define OFF_CF   (OFF_SS + 16)                   // 5 f32 coeffs
#define OFF_ACC  (OFF_CF + 32)                   // 3 f64 category sums
#define OFF_CNT  (OFF_ACC + 24)                  // 2 u32 completion counters
#define OFF_END  (OFF_CNT + 8)

// ---- prep: f32 -> bf16 roundtrip, row sq-norms, col sums; last block -> coeffs ----
__global__ __launch_bounds__(256) void prep_kernel(
    const float* __restrict__ src, const float* __restrict__ tgt,
    __hip_bfloat16* __restrict__ xb, float* __restrict__ sq,
    float* __restrict__ colsum, float* __restrict__ Ssum,
    float* __restrict__ coeffs, unsigned int* __restrict__ cnt)
{
  __shared__ float scol[256];
  __shared__ float sS[4];
  __shared__ int slast;
  const int tid = threadIdx.x, wave = tid >> 6, lane = tid & 63;
  scol[tid] = 0.f;
  if (tid < 4) sS[tid] = 0.f;
  __syncthreads();

  float cacc0 = 0.f, cacc1 = 0.f, cacc2 = 0.f, cacc3 = 0.f;
  float swave = 0.f;
  const int rowbase = blockIdx.x * 32 + wave * 8;
  for (int rr = 0; rr < 8; ++rr) {
    const int row = rowbase + rr;
    const float* p = (row < NSRC) ? (src + (size_t)row * D)
                                  : (tgt + (size_t)(row - NSRC) * D);
    const float4 v = reinterpret_cast<const float4*>(p)[lane];
    const __hip_bfloat16 b0 = __float2bfloat16(v.x), b1 = __float2bfloat16(v.y),
                         b2 = __float2bfloat16(v.z), b3 = __float2bfloat16(v.w);
    ushort4 h;
    h.x = *(const unsigned short*)&b0; h.y = *(const unsigned short*)&b1;
    h.z = *(const unsigned short*)&b2; h.w = *(const unsigned short*)&b3;
    reinterpret_cast<ushort4*>(xb + (size_t)row * D)[lane] = h;
    const float f0 = __bfloat162float(b0), f1 = __bfloat162float(b1),
                f2 = __bfloat162float(b2), f3 = __bfloat162float(b3);
    cacc0 += f0; cacc1 += f1; cacc2 += f2; cacc3 += f3;
    float s = f0 * f0 + f1 * f1 + f2 * f2 + f3 * f3;
    #pragma unroll
    for (int off = 32; off > 0; off >>= 1) s += __shfl_down(s, off);
    if (lane == 0) { sq[row] = s; swave += s; }
  }
  atomicAdd(&scol[lane * 4 + 0], cacc0);
  atomicAdd(&scol[lane * 4 + 1], cacc1);
  atomicAdd(&scol[lane * 4 + 2], cacc2);
  atomicAdd(&scol[lane * 4 + 3], cacc3);
  if (lane == 0) sS[wave] = swave;
  __syncthreads();
  atomicAdd(&colsum[tid], scol[tid]);
  if (tid == 0) {
    atomicAdd(Ssum, sS[0] + sS[1] + sS[2] + sS[3]);
    __threadfence();
    slast = (atomicAdd(cnt, 1u) == (unsigned)(gridDim.x - 1));
  }
  __syncthreads();
  if (slast) {
    const float cv = atomicAdd(&colsum[tid], 0.f);  // coherent read-back
    scol[tid] = cv * cv;
    __syncthreads();
    for (int off = 128; off > 0; off >>= 1) {
      if (tid < off) scol[tid] += scol[tid + off];
      __syncthreads();
    }
    if (tid == 0) {
      const float S = atomicAdd(Ssum, 0.f);
      const double sumd2 = 2.0 * (double)NTOT * (double)S - 2.0 * (double)scol[0];
      const double bw = sumd2 / ((double)NTOT * (double)NTOT - (double)NTOT) / 4.0;
      #pragma unroll
      for (int i = 0; i < 5; ++i)
        coeffs[i] = (float)(-1.4426950408889634 / (bw * (double)(1 << i)));
    }
  }
}

// ---- main: triangular 128x128 tiles, bf16 MFMA + 2-exp squaring epilogue ----
__global__ __launch_bounds__(256) void pair_kernel(
    const __hip_bfloat16* __restrict__ xb, const float* __restrict__ sq,
    const float* __restrict__ coeffs, double* __restrict__ accum,
    unsigned int* __restrict__ cnt, float* __restrict__ out)
{
  // decode triangular index -> (bi, bj), bi <= bj
  const int idx = blockIdx.x;
  int bi = (int)(64.5 - sqrt(64.5 * 64.5 - 2.0 * (double)idx));
  while (NT * (bi + 1) - (bi + 1) * bi / 2 <= idx) ++bi;
  while (NT * bi - bi * (bi - 1) / 2 > idx) --bi;
  const int bj = bi + (idx - (NT * bi - bi * (bi - 1) / 2));

  __shared__ __align__(16) short lA[128 * 64];
  __shared__ __align__(16) short lB[128 * 64];
  __shared__ float sqA[128], sqB[128], wsum[4];

  const int tid = threadIdx.x;
  const int wave = tid >> 6, lane = tid & 63;
  const int wr = wave >> 1, wc = wave & 1;

  if (tid < 128) sqA[tid] = sq[bi * 128 + tid];
  else           sqB[tid - 128] = sq[bj * 128 + (tid - 128)];

  const float c1 = coeffs[1], c4 = coeffs[4];

  f32x4 acc[4][4];
  #pragma unroll
  for (int mi = 0; mi < 4; ++mi)
    #pragma unroll
    for (int nj = 0; nj < 4; ++nj)
      acc[mi][nj] = (f32x4){0.f, 0.f, 0.f, 0.f};

  // global_load_lds writes linear (wave base + lane*16); LDS gets the
  // st-swizzled layout by pre-swizzling the per-lane GLOBAL source column
  // (rule 21: inverse-swz source + swz read; XOR is an involution).
  const int srow = lane >> 3;
  const int scol_e = ((lane & 7) ^ (lane >> 3)) * 8;
  const __hip_bfloat16* gA = xb + (size_t)(bi * 128 + wave * 8 + srow) * D + scol_e;
  const __hip_bfloat16* gB = xb + (size_t)(bj * 128 + wave * 8 + srow) * D + scol_e;
  char* ldsA = (char*)lA + (wave * 8) * 128;
  char* ldsB = (char*)lB + (wave * 8) * 128;

  for (int kk = 0; kk < D; kk += 64) {
    __syncthreads();  // previous iter's ds_reads done before overwrite
    #pragma unroll
    for (int q = 0; q < 4; ++q) {
      __builtin_amdgcn_global_load_lds(
          (const GLB_AS uint32_t*)(gA + (size_t)q * 32 * D + kk),
          (LDS_AS uint32_t*)(ldsA + q * 32 * 128), 16, 0, 0);
      __builtin_amdgcn_global_load_lds(
          (const GLB_AS uint32_t*)(gB + (size_t)q * 32 * D + kk),
          (LDS_AS uint32_t*)(ldsB + q * 32 * 128), 16, 0, 0);
    }
    __syncthreads();  // drains vmcnt(0) before barrier

    #pragma unroll
    for (int ks = 0; ks < 2; ++ks) {
      bf16x8 af[4], bfr[4];
      const int kb = (ks * 32 + (lane >> 4) * 8) * 2;
      #pragma unroll
      for (int mi = 0; mi < 4; ++mi) {
        const int row = wr * 64 + mi * 16 + (lane & 15);
        af[mi] = *(const bf16x8*)((const char*)lA + row * 128 + (kb ^ ((row & 7) << 4)));
      }
      #pragma unroll
      for (int nj = 0; nj < 4; ++nj) {
        const int row = wc * 64 + nj * 16 + (lane & 15);
        bfr[nj] = *(const bf16x8*)((const char*)lB + row * 128 + (kb ^ ((row & 7) << 4)));
      }
      #pragma unroll
      for (int mi = 0; mi < 4; ++mi)
        #pragma unroll
        for (int nj = 0; nj < 4; ++nj)
          acc[mi][nj] = __builtin_amdgcn_mfma_f32_16x16x32_bf16(
              af[mi], bfr[nj], acc[mi][nj], 0, 0, 0);
    }
  }

  // epilogue: d2 = sq_i + sq_j - 2*gram
  // kernels: e_t = exp2(d2*c_t), c_t = c_{t+1}*2  =>  e_t = e_{t+1}^2.
  // Compute e4, e1 directly; e3=e4^2, e2=e3^2, e0=e1^2 (amplification <= 4x).
  float tsum = 0.f;
  const int r0 = (lane >> 4) * 4;
  const int cc = lane & 15;
  #pragma unroll
  for (int mi = 0; mi < 4; ++mi) {
    #pragma unroll
    for (int r = 0; r < 4; ++r) {
      const float si = sqA[wr * 64 + mi * 16 + r0 + r];
      #pragma unroll
      for (int nj = 0; nj < 4; ++nj) {
        const float sj = sqB[wc * 64 + nj * 16 + cc];
        float d2 = fmaf(-2.f, acc[mi][nj][r], si + sj);
        d2 = fmaxf(d2, 0.f);
        const float e4 = EXP2F(d2 * c4);
        const float e1 = EXP2F(d2 * c1);
        const float e3 = e4 * e4;
        const float e2 = e3 * e3;
        const float e0 = e1 * e1;
        tsum += ((e4 + e3) + (e2 + e1)) + e0;
      }
    }
  }
  #pragma unroll
  for (int off = 32; off > 0; off >>= 1) tsum += __shfl_down(tsum, off);
  if (lane == 0) wsum[wave] = tsum;
  __syncthreads();
  if (tid == 0) {
    const float bsum = wsum[0] + wsum[1] + wsum[2] + wsum[3];
    const int cat = (bi >= 32) ? 1 : ((bj >= 32) ? 2 : 0);
    const double w = (bi == bj) ? 1.0 : 2.0;
    atomicAdd(&accum[cat], w * (double)bsum);
    __threadfence();
    if (atomicAdd(cnt, 1u) == (unsigned)(NTRI - 1)) {
      const double a0 = atomicAdd(&accum[0], 0.0);
      const double a1 = atomicAdd(&accum[1], 0.0);
      const double a2 = atomicAdd(&accum[2], 0.0);
      out[0] = (float)((a0 + a1 - a2) / ((double)NSRC * (double)NSRC));
    }
  }
}

extern "C" void kernel_launch(void* const* d_in, const int* in_sizes, int n_in,
                              void* d_out, int out_size, void* d_ws, size_t ws_size,
                              hipStream_t stream) {
  (void)in_sizes; (void)n_in; (void)out_size; (void)ws_size;
  const float* src = (const float*)d_in[0];
  const float* tgt = (const float*)d_in[1];
  char* ws = (char*)d_ws;
  __hip_bfloat16* xb = (__hip_bfloat16*)(ws + OFF_XB);
  float* sq      = (float*)(ws + OFF_SQ);
  float* colsum  = (float*)(ws + OFF_COL);
  float* Ssum    = (float*)(ws + OFF_SS);
  float* coeffs  = (float*)(ws + OFF_CF);
  double* accum  = (double*)(ws + OFF_ACC);
  unsigned int* cnts = (unsigned int*)(ws + OFF_CNT);

  hipMemsetAsync(ws + OFF_COL, 0, OFF_END - OFF_COL, stream);
  prep_kernel<<<256, 256, 0, stream>>>(src, tgt, xb, sq, colsum, Ssum, coeffs, cnts + 0);
  pair_kernel<<<NTRI, 256, 0, stream>>>(xb, sq, coeffs, accum, cnts + 1, (float*)d_out);
}

// Round 3
// 69.684 us; speedup vs baseline: 1.3227x; 1.2652x over previous
//
#include <hip/hip_runtime.h>
#include <hip/hip_bf16.h>
#include <stdint.h>
#include <math.h>

#define D     256
#define NTOT  8192
#define NSRC  4096
#define NT    64                  // 64 tiles of 128 rows
#define NTRI  (NT * (NT + 1) / 2) // 2080 upper-tri tiles
#define PREPB 64                  // prep blocks (128 rows each)

using bf16x8 = __attribute__((ext_vector_type(8))) short;
using f32x4  = __attribute__((ext_vector_type(4))) float;

#define GLB_AS __attribute__((address_space(1)))
#define LDS_AS __attribute__((address_space(3)))

#if __has_builtin(__builtin_amdgcn_exp2f)
#define EXP2F __builtin_amdgcn_exp2f
#else
#define EXP2F exp2f
#endif

// workspace layout (bytes) — every region is fully written before read on
// every launch (no counters, no atomics) => poison-safe and deterministic.
#define OFF_XB   ((size_t)0)                       // 4 MB bf16 X
#define OFF_SQ   ((size_t)NTOT * D * 2)            // 8192 f32 row sq-norms
#define OFF_CP   (OFF_SQ + (size_t)NTOT * 4)       // colsum parts [PREPB][256] f32
#define OFF_SP   (OFF_CP + (size_t)PREPB * 256 * 4)// sq-sum parts [PREPB] f32
#define OFF_CF   (OFF_SP + (size_t)PREPB * 4)      // 1 f32 coeff (c4)
#define OFF_PT   (OFF_CF + 32)                     // per-tile partials [NTRI] f32
#define OFF_END  (OFF_PT + (size_t)NTRI * 4)

// ---- prep: f32 -> bf16 roundtrip, row sq-norms, per-block col/sq partials ----
__global__ __launch_bounds__(256) void prep_kernel(
    const float* __restrict__ src, const float* __restrict__ tgt,
    __hip_bfloat16* __restrict__ xb, float* __restrict__ sq,
    float* __restrict__ colpart, float* __restrict__ sqpart)
{
  __shared__ float scol4[4][256];
  __shared__ float sSl[4];
  const int tid = threadIdx.x, wave = tid >> 6, lane = tid & 63;
  const int row0 = blockIdx.x * 128 + wave * 32;   // whole block is one side
  const float* p0 = (row0 < NSRC) ? (src + (size_t)row0 * D)
                                  : (tgt + (size_t)(row0 - NSRC) * D);
  float c0 = 0.f, c1 = 0.f, c2 = 0.f, c3 = 0.f, swave = 0.f;
  for (int rr = 0; rr < 32; ++rr) {
    const int row = row0 + rr;
    const float4 v = reinterpret_cast<const float4*>(p0 + (size_t)rr * D)[lane];
    const __hip_bfloat16 b0 = __float2bfloat16(v.x), b1 = __float2bfloat16(v.y),
                         b2 = __float2bfloat16(v.z), b3 = __float2bfloat16(v.w);
    ushort4 h;
    h.x = *(const unsigned short*)&b0; h.y = *(const unsigned short*)&b1;
    h.z = *(const unsigned short*)&b2; h.w = *(const unsigned short*)&b3;
    reinterpret_cast<ushort4*>(xb + (size_t)row * D)[lane] = h;
    const float f0 = __bfloat162float(b0), f1 = __bfloat162float(b1),
                f2 = __bfloat162float(b2), f3 = __bfloat162float(b3);
    c0 += f0; c1 += f1; c2 += f2; c3 += f3;
    float s = f0 * f0 + f1 * f1 + f2 * f2 + f3 * f3;
    #pragma unroll
    for (int off = 32; off > 0; off >>= 1) s += __shfl_down(s, off);
    if (lane == 0) { sq[row] = s; swave += s; }
  }
  scol4[wave][lane * 4 + 0] = c0;
  scol4[wave][lane * 4 + 1] = c1;
  scol4[wave][lane * 4 + 2] = c2;
  scol4[wave][lane * 4 + 3] = c3;
  if (lane == 0) sSl[wave] = swave;
  __syncthreads();
  colpart[blockIdx.x * 256 + tid] =
      scol4[0][tid] + scol4[1][tid] + scol4[2][tid] + scol4[3][tid];
  if (tid == 0) sqpart[blockIdx.x] = sSl[0] + sSl[1] + sSl[2] + sSl[3];
}

// ---- bw: reduce partials -> bandwidth coefficient c4 ----
__global__ __launch_bounds__(256) void bw_kernel(
    const float* __restrict__ colpart, const float* __restrict__ sqpart,
    float* __restrict__ cf)
{
  __shared__ float red[256];
  const int t = threadIdx.x;
  float cs = 0.f;
  for (int b = 0; b < PREPB; ++b) cs += colpart[b * 256 + t];
  red[t] = cs * cs;
  __syncthreads();
  for (int off = 128; off > 0; off >>= 1) {
    if (t < off) red[t] += red[t + off];
    __syncthreads();
  }
  const float s2 = red[0];
  __syncthreads();
  red[t] = (t < PREPB) ? sqpart[t] : 0.f;
  __syncthreads();
  for (int off = 128; off > 0; off >>= 1) {
    if (t < off) red[t] += red[t + off];
    __syncthreads();
  }
  if (t == 0) {
    const double sumd2 = 2.0 * (double)NTOT * (double)red[0] - 2.0 * (double)s2;
    const double bw = sumd2 / ((double)NTOT * (double)NTOT - (double)NTOT) / 4.0;
    cf[0] = (float)(-1.4426950408889634 / (bw * 16.0));  // c4
  }
}

// ---- main: triangular 128x128 tiles, pipelined staging, 1-exp epilogue ----
__global__ __launch_bounds__(256) void pair_kernel(
    const __hip_bfloat16* __restrict__ xb, const float* __restrict__ sq,
    const float* __restrict__ cf, float* __restrict__ part)
{
  const int idx = blockIdx.x;
  const float rr = sqrtf(4160.25f - 2.0f * (float)idx);
  int bi = (int)(64.5f - rr);
  while (NT * (bi + 1) - (bi + 1) * bi / 2 <= idx) ++bi;
  while (NT * bi - bi * (bi - 1) / 2 > idx) --bi;
  const int bj = bi + (idx - (NT * bi - bi * (bi - 1) / 2));

  __shared__ __align__(16) short lA[2][128 * 64];
  __shared__ __align__(16) short lB[2][128 * 64];
  __shared__ float sqA[128], sqB[128], wsum[4];

  const int tid = threadIdx.x, wave = tid >> 6, lane = tid & 63;
  const int wr = wave >> 1, wc = wave & 1;

  if (tid < 128) sqA[tid] = sq[bi * 128 + tid];
  else           sqB[tid - 128] = sq[bj * 128 + (tid - 128)];

  // global_load_lds writes linear (wave base + lane*16); the st-swizzled LDS
  // layout comes from pre-swizzling the per-lane GLOBAL source column
  // (rule 21: inverse-swz source + swz read; XOR is an involution).
  const int srow = lane >> 3;
  const int scol_e = ((lane & 7) ^ srow) * 8;
  const __hip_bfloat16* gA = xb + (size_t)(bi * 128 + wave * 8 + srow) * D + scol_e;
  const __hip_bfloat16* gB = xb + (size_t)(bj * 128 + wave * 8 + srow) * D + scol_e;

  f32x4 acc[4][4];
  #pragma unroll
  for (int mi = 0; mi < 4; ++mi)
    #pragma unroll
    for (int nj = 0; nj < 4; ++nj)
      acc[mi][nj] = (f32x4){0.f, 0.f, 0.f, 0.f};

#define STAGE(buf, t) do {                                                   \
    char* dA_ = (char*)lA[buf] + (wave * 8) * 128;                           \
    char* dB_ = (char*)lB[buf] + (wave * 8) * 128;                           \
    _Pragma("unroll")                                                        \
    for (int q = 0; q < 4; ++q) {                                            \
      __builtin_amdgcn_global_load_lds(                                      \
          (const GLB_AS uint32_t*)(gA + (size_t)q * 32 * D + (t) * 64),      \
          (LDS_AS uint32_t*)(dA_ + q * 32 * 128), 16, 0, 0);                 \
      __builtin_amdgcn_global_load_lds(                                      \
          (const GLB_AS uint32_t*)(gB + (size_t)q * 32 * D + (t) * 64),      \
          (LDS_AS uint32_t*)(dB_ + q * 32 * 128), 16, 0, 0);                 \
    } } while (0)

  STAGE(0, 0);
  __syncthreads();                       // tile 0 staged
  #pragma unroll
  for (int t = 0; t < 4; ++t) {
    if (t < 3) STAGE((t + 1) & 1, t + 1);  // prefetch next tile (overlaps MFMA)
    const char* bufA = (const char*)lA[t & 1];
    const char* bufB = (const char*)lB[t & 1];
    #pragma unroll
    for (int ks = 0; ks < 2; ++ks) {
      bf16x8 af[4], bfr[4];
      const int kb = (ks * 32 + (lane >> 4) * 8) * 2;
      #pragma unroll
      for (int mi = 0; mi < 4; ++mi) {
        const int row = wr * 64 + mi * 16 + (lane & 15);
        af[mi] = *(const bf16x8*)(bufA + row * 128 + (kb ^ ((row & 7) << 4)));
      }
      #pragma unroll
      for (int nj = 0; nj < 4; ++nj) {
        const int row = wc * 64 + nj * 16 + (lane & 15);
        bfr[nj] = *(const bf16x8*)(bufB + row * 128 + (kb ^ ((row & 7) << 4)));
      }
      #pragma unroll
      for (int mi = 0; mi < 4; ++mi)
        #pragma unroll
        for (int nj = 0; nj < 4; ++nj)
          acc[mi][nj] = __builtin_amdgcn_mfma_f32_16x16x32_bf16(
              af[mi], bfr[nj], acc[mi][nj], 0, 0, 0);
    }
    if (t < 3) __syncthreads();          // next tile staged; prev reads done
  }
#undef STAGE

  // epilogue: d2 = si + sj - 2*gram; e_t chain from single exp:
  // e4 = exp2(d2*c4); e3=e4^2; e2=e3^2; e1=e2^2; e0=e1^2  (amp <= 16x)
  const float c4 = cf[0];
  const int r0 = (lane >> 4) * 4, cc = lane & 15;
  float sjv[4];
  #pragma unroll
  for (int nj = 0; nj < 4; ++nj) sjv[nj] = sqB[wc * 64 + nj * 16 + cc];
  float tsum = 0.f;
  #pragma unroll
  for (int mi = 0; mi < 4; ++mi) {
    #pragma unroll
    for (int r = 0; r < 4; ++r) {
      const float si = sqA[wr * 64 + mi * 16 + r0 + r];
      #pragma unroll
      for (int nj = 0; nj < 4; ++nj) {
        float d2 = fmaf(-2.f, acc[mi][nj][r], si + sjv[nj]);
        d2 = fmaxf(d2, 0.f);
        const float e4 = EXP2F(d2 * c4);
        const float e3 = e4 * e4, e2 = e3 * e3;
        const float e1 = e2 * e2, e0 = e1 * e1;
        tsum += ((e4 + e3) + (e2 + e1)) + e0;
      }
    }
  }
  #pragma unroll
  for (int off = 32; off > 0; off >>= 1) tsum += __shfl_down(tsum, off);
  if (lane == 0) wsum[wave] = tsum;
  __syncthreads();
  if (tid == 0) part[idx] = wsum[0] + wsum[1] + wsum[2] + wsum[3];
}

// ---- out: deterministic tree-reduce of tile partials ----
__global__ __launch_bounds__(256) void out_kernel(
    const float* __restrict__ part, float* __restrict__ out)
{
  __shared__ double red0[256], red1[256], red2[256];
  const int t = threadIdx.x;
  double a0 = 0.0, a1 = 0.0, a2 = 0.0;
  for (int j = t; j < NTRI; j += 256) {
    const float r1 = sqrtf(4160.25f - 2.0f * (float)j);
    int bi = (int)(64.5f - r1);
    while (NT * (bi + 1) - (bi + 1) * bi / 2 <= j) ++bi;
    while (NT * bi - bi * (bi - 1) / 2 > j) --bi;
    const int bj = bi + (j - (NT * bi - bi * (bi - 1) / 2));
    const double w = (bi == bj) ? 1.0 : 2.0;
    const double v = w * (double)part[j];
    if (bi >= 32) a1 += v;
    else if (bj >= 32) a2 += v;
    else a0 += v;
  }
  red0[t] = a0; red1[t] = a1; red2[t] = a2;
  __syncthreads();
  for (int off = 128; off > 0; off >>= 1) {
    if (t < off) {
      red0[t] += red0[t + off];
      red1[t] += red1[t + off];
      red2[t] += red2[t + off];
    }
    __syncthreads();
  }
  if (t == 0)
    out[0] = (float)((red0[0] + red1[0] - red2[0]) /
                     ((double)NSRC * (double)NSRC));
}

extern "C" void kernel_launch(void* const* d_in, const int* in_sizes, int n_in,
                              void* d_out, int out_size, void* d_ws, size_t ws_size,
                              hipStream_t stream) {
  (void)in_sizes; (void)n_in; (void)out_size; (void)ws_size;
  const float* src = (const float*)d_in[0];
  const float* tgt = (const float*)d_in[1];
  char* ws = (char*)d_ws;
  __hip_bfloat16* xb = (__hip_bfloat16*)(ws + OFF_XB);
  float* sq      = (float*)(ws + OFF_SQ);
  float* colpart = (float*)(ws + OFF_CP);
  float* sqpart  = (float*)(ws + OFF_SP);
  float* cf      = (float*)(ws + OFF_CF);
  float* part    = (float*)(ws + OFF_PT);

  prep_kernel<<<PREPB, 256, 0, stream>>>(src, tgt, xb, sq, colpart, sqpart);
  bw_kernel<<<1, 256, 0, stream>>>(colpart, sqpart, cf);
  pair_kernel<<<NTRI, 256, 0, stream>>>(xb, sq, cf, part);
  out_kernel<<<1, 256, 0, stream>>>(part, (float*)d_out);
}

// Round 4
// 64.236 us; speedup vs baseline: 1.4349x; 1.0848x over previous
//
#include <hip/hip_runtime.h>
#include <hip/hip_bf16.h>
#include <stdint.h>
#include <math.h>

#define D     256
#define NTOT  8192
#define NSRC  4096
#define NT    64                  // 64 tiles of 128 rows
#define NTRI  (NT * (NT + 1) / 2) // 2080 upper-tri tiles
#define PREPB 128                 // prep blocks (64 rows each)

using bf16x8 = __attribute__((ext_vector_type(8))) short;
using f32x4  = __attribute__((ext_vector_type(4))) float;

#define GLB_AS __attribute__((address_space(1)))
#define LDS_AS __attribute__((address_space(3)))

#if __has_builtin(__builtin_amdgcn_exp2f)
#define EXP2F __builtin_amdgcn_exp2f
#else
#define EXP2F exp2f
#endif

// workspace layout (bytes) — every region fully written before read each
// launch (no atomics, no counters) => poison-safe and deterministic.
#define OFF_XB   ((size_t)0)                        // 4 MB bf16 X
#define OFF_SQ   ((size_t)NTOT * D * 2)             // 8192 f32 row sq-norms
#define OFF_CP   (OFF_SQ + (size_t)NTOT * 4)        // colsum parts [PREPB][256]
#define OFF_SP   (OFF_CP + (size_t)PREPB * 256 * 4) // sq-sum parts [PREPB]
#define OFF_CF   (OFF_SP + (size_t)PREPB * 4)       // 1 f32 coeff (c4)
#define OFF_PT   (OFF_CF + 32)                      // per-tile partials [NTRI]
#define OFF_END  (OFF_PT + (size_t)NTRI * 4)

// ---- prep: f32 -> bf16 roundtrip, row sq-norms, per-block col/sq partials ----
__global__ __launch_bounds__(256) void prep_kernel(
    const float* __restrict__ src, const float* __restrict__ tgt,
    __hip_bfloat16* __restrict__ xb, float* __restrict__ sq,
    float* __restrict__ colpart, float* __restrict__ sqpart)
{
  __shared__ float scol4[4][256];
  __shared__ float sSl[4];
  const int tid = threadIdx.x, wave = tid >> 6, lane = tid & 63;
  const int row0 = blockIdx.x * 64 + wave * 16;    // 64-row blocks never straddle sides
  const float* p0 = (row0 < NSRC) ? (src + (size_t)row0 * D)
                                  : (tgt + (size_t)(row0 - NSRC) * D);
  float c0 = 0.f, c1 = 0.f, c2 = 0.f, c3 = 0.f, swave = 0.f;
  for (int rr = 0; rr < 16; ++rr) {
    const int row = row0 + rr;
    const float4 v = reinterpret_cast<const float4*>(p0 + (size_t)rr * D)[lane];
    const __hip_bfloat16 b0 = __float2bfloat16(v.x), b1 = __float2bfloat16(v.y),
                         b2 = __float2bfloat16(v.z), b3 = __float2bfloat16(v.w);
    ushort4 h;
    h.x = *(const unsigned short*)&b0; h.y = *(const unsigned short*)&b1;
    h.z = *(const unsigned short*)&b2; h.w = *(const unsigned short*)&b3;
    reinterpret_cast<ushort4*>(xb + (size_t)row * D)[lane] = h;
    const float f0 = __bfloat162float(b0), f1 = __bfloat162float(b1),
                f2 = __bfloat162float(b2), f3 = __bfloat162float(b3);
    c0 += f0; c1 += f1; c2 += f2; c3 += f3;
    float s = f0 * f0 + f1 * f1 + f2 * f2 + f3 * f3;
    #pragma unroll
    for (int off = 32; off > 0; off >>= 1) s += __shfl_down(s, off);
    if (lane == 0) { sq[row] = s; swave += s; }
  }
  scol4[wave][lane * 4 + 0] = c0;
  scol4[wave][lane * 4 + 1] = c1;
  scol4[wave][lane * 4 + 2] = c2;
  scol4[wave][lane * 4 + 3] = c3;
  if (lane == 0) sSl[wave] = swave;
  __syncthreads();
  colpart[blockIdx.x * 256 + tid] =
      scol4[0][tid] + scol4[1][tid] + scol4[2][tid] + scol4[3][tid];
  if (tid == 0) sqpart[blockIdx.x] = sSl[0] + sSl[1] + sSl[2] + sSl[3];
}

// ---- bw: reduce partials -> bandwidth coefficient c4 ----
__global__ __launch_bounds__(256) void bw_kernel(
    const float* __restrict__ colpart, const float* __restrict__ sqpart,
    float* __restrict__ cf)
{
  __shared__ float red[256];
  const int t = threadIdx.x;
  float cs = 0.f;
  for (int b = 0; b < PREPB; ++b) cs += colpart[b * 256 + t];  // coalesced
  red[t] = cs * cs;
  __syncthreads();
  for (int off = 128; off > 0; off >>= 1) {
    if (t < off) red[t] += red[t + off];
    __syncthreads();
  }
  const float s2 = red[0];
  __syncthreads();
  red[t] = (t < PREPB) ? sqpart[t] : 0.f;
  __syncthreads();
  for (int off = 128; off > 0; off >>= 1) {
    if (t < off) red[t] += red[t + off];
    __syncthreads();
  }
  if (t == 0) {
    const double sumd2 = 2.0 * (double)NTOT * (double)red[0] - 2.0 * (double)s2;
    const double bw = sumd2 / ((double)NTOT * (double)NTOT - (double)NTOT) / 4.0;
    cf[0] = (float)(-1.4426950408889634 / (bw * 16.0));  // c4
  }
}

// ---- main: triangular 128x128 tiles, counted-vmcnt pipeline, 1-exp epilogue ----
__global__ __launch_bounds__(256) void pair_kernel(
    const __hip_bfloat16* __restrict__ xb, const float* __restrict__ sq,
    const float* __restrict__ cf, float* __restrict__ part)
{
  const int idx = blockIdx.x;
  const float rr = sqrtf(4160.25f - 2.0f * (float)idx);
  int bi = (int)(64.5f - rr);
  while (NT * (bi + 1) - (bi + 1) * bi / 2 <= idx) ++bi;
  while (NT * bi - bi * (bi - 1) / 2 > idx) --bi;
  const int bj = bi + (idx - (NT * bi - bi * (bi - 1) / 2));

  __shared__ __align__(16) short lA[2][128 * 64];
  __shared__ __align__(16) short lB[2][128 * 64];
  __shared__ float sqA[128], sqB[128], wsum[4];

  const int tid = threadIdx.x, wave = tid >> 6, lane = tid & 63;
  const int wr = wave >> 1, wc = wave & 1;

  const float c4 = cf[0];                       // issue early (oldest in vm queue)
  if (tid < 128) sqA[tid] = sq[bi * 128 + tid];
  else           sqB[tid - 128] = sq[bj * 128 + (tid - 128)];

  // global_load_lds writes linear (wave base + lane*16); st-swizzled LDS layout
  // via pre-swizzled per-lane GLOBAL source column (rule 21: inverse-swz source
  // + swz read; XOR is an involution).
  const int srow = lane >> 3;
  const int scol_e = ((lane & 7) ^ srow) * 8;
  const __hip_bfloat16* gA = xb + (size_t)(bi * 128 + wave * 8 + srow) * D + scol_e;
  const __hip_bfloat16* gB = xb + (size_t)(bj * 128 + wave * 8 + srow) * D + scol_e;

  f32x4 acc[4][4];
  #pragma unroll
  for (int mi = 0; mi < 4; ++mi)
    #pragma unroll
    for (int nj = 0; nj < 4; ++nj)
      acc[mi][nj] = (f32x4){0.f, 0.f, 0.f, 0.f};

#define STAGE(buf, t) do {                                                   \
    char* dA_ = (char*)lA[buf] + (wave * 8) * 128;                           \
    char* dB_ = (char*)lB[buf] + (wave * 8) * 128;                           \
    _Pragma("unroll")                                                        \
    for (int q = 0; q < 4; ++q) {                                            \
      __builtin_amdgcn_global_load_lds(                                      \
          (const GLB_AS uint32_t*)(gA + (size_t)q * 32 * D + (t) * 64),      \
          (LDS_AS uint32_t*)(dA_ + q * 32 * 128), 16, 0, 0);                 \
      __builtin_amdgcn_global_load_lds(                                      \
          (const GLB_AS uint32_t*)(gB + (size_t)q * 32 * D + (t) * 64),      \
          (LDS_AS uint32_t*)(dB_ + q * 32 * 128), 16, 0, 0);                 \
    } } while (0)

  STAGE(0, 0);   // 8 loads in flight
  #pragma unroll
  for (int t = 0; t < 4; ++t) {
    // issue next tile BEFORE this tile's wait => its 8 loads stay in flight
    // across the barrier (counted vmcnt, never a full drain in steady state)
    if (t < 3) STAGE((t + 1) & 1, t + 1);
    __builtin_amdgcn_sched_barrier(0);
    if (t == 0)      asm volatile("s_waitcnt vmcnt(8) lgkmcnt(0)" ::: "memory");
    else if (t < 3)  asm volatile("s_waitcnt vmcnt(8)" ::: "memory");
    else             asm volatile("s_waitcnt vmcnt(0)" ::: "memory");
    __builtin_amdgcn_s_barrier();          // all waves: tile-t data resident
    __builtin_amdgcn_sched_barrier(0);

    const char* bufA = (const char*)lA[t & 1];
    const char* bufB = (const char*)lB[t & 1];
    #pragma unroll
    for (int ks = 0; ks < 2; ++ks) {
      bf16x8 af[4], bfr[4];
      const int kb = (ks * 32 + (lane >> 4) * 8) * 2;
      #pragma unroll
      for (int mi = 0; mi < 4; ++mi) {
        const int row = wr * 64 + mi * 16 + (lane & 15);
        af[mi] = *(const bf16x8*)(bufA + row * 128 + (kb ^ ((row & 7) << 4)));
      }
      #pragma unroll
      for (int nj = 0; nj < 4; ++nj) {
        const int row = wc * 64 + nj * 16 + (lane & 15);
        bfr[nj] = *(const bf16x8*)(bufB + row * 128 + (kb ^ ((row & 7) << 4)));
      }
      #pragma unroll
      for (int mi = 0; mi < 4; ++mi)
        #pragma unroll
        for (int nj = 0; nj < 4; ++nj)
          acc[mi][nj] = __builtin_amdgcn_mfma_f32_16x16x32_bf16(
              af[mi], bfr[nj], acc[mi][nj], 0, 0, 0);
    }
    if (t < 3) {
      __builtin_amdgcn_sched_barrier(0);
      __builtin_amdgcn_s_barrier();        // all waves done reading buf[t&1]
      __builtin_amdgcn_sched_barrier(0);   // before next STAGE overwrites it
    }
  }
#undef STAGE

  // epilogue: d2 = si + sj - 2*gram; e4 = exp2(d2*c4); e_{t-1} = e_t^2
  const int r0 = (lane >> 4) * 4, cc = lane & 15;
  float sjv[4];
  #pragma unroll
  for (int nj = 0; nj < 4; ++nj) sjv[nj] = sqB[wc * 64 + nj * 16 + cc];
  float tsum = 0.f;
  #pragma unroll
  for (int mi = 0; mi < 4; ++mi) {
    #pragma unroll
    for (int r = 0; r < 4; ++r) {
      const float si = sqA[wr * 64 + mi * 16 + r0 + r];
      #pragma unroll
      for (int nj = 0; nj < 4; ++nj) {
        float d2 = fmaf(-2.f, acc[mi][nj][r], si + sjv[nj]);
        d2 = fmaxf(d2, 0.f);
        const float e4 = EXP2F(d2 * c4);
        const float e3 = e4 * e4, e2 = e3 * e3;
        const float e1 = e2 * e2, e0 = e1 * e1;
        tsum += ((e4 + e3) + (e2 + e1)) + e0;
      }
    }
  }
  #pragma unroll
  for (int off = 32; off > 0; off >>= 1) tsum += __shfl_down(tsum, off);
  if (lane == 0) wsum[wave] = tsum;
  __syncthreads();
  if (tid == 0) part[idx] = wsum[0] + wsum[1] + wsum[2] + wsum[3];
}

// ---- out: deterministic tree-reduce of tile partials ----
__global__ __launch_bounds__(256) void out_kernel(
    const float* __restrict__ part, float* __restrict__ out)
{
  __shared__ double red0[256], red1[256], red2[256];
  const int t = threadIdx.x;
  double a0 = 0.0, a1 = 0.0, a2 = 0.0;
  for (int j = t; j < NTRI; j += 256) {
    const float r1 = sqrtf(4160.25f - 2.0f * (float)j);
    int bi = (int)(64.5f - r1);
    while (NT * (bi + 1) - (bi + 1) * bi / 2 <= j) ++bi;
    while (NT * bi - bi * (bi - 1) / 2 > j) --bi;
    const int bj = bi + (j - (NT * bi - bi * (bi - 1) / 2));
    const double w = (bi == bj) ? 1.0 : 2.0;
    const double v = w * (double)part[j];
    if (bi >= 32) a1 += v;
    else if (bj >= 32) a2 += v;
    else a0 += v;
  }
  red0[t] = a0; red1[t] = a1; red2[t] = a2;
  __syncthreads();
  for (int off = 128; off > 0; off >>= 1) {
    if (t < off) {
      red0[t] += red0[t + off];
      red1[t] += red1[t + off];
      red2[t] += red2[t + off];
    }
    __syncthreads();
  }
  if (t == 0)
    out[0] = (float)((red0[0] + red1[0] - red2[0]) /
                     ((double)NSRC * (double)NSRC));
}

extern "C" void kernel_launch(void* const* d_in, const int* in_sizes, int n_in,
                              void* d_out, int out_size, void* d_ws, size_t ws_size,
                              hipStream_t stream) {
  (void)in_sizes; (void)n_in; (void)out_size; (void)ws_size;
  const float* src = (const float*)d_in[0];
  const float* tgt = (const float*)d_in[1];
  char* ws = (char*)d_ws;
  __hip_bfloat16* xb = (__hip_bfloat16*)(ws + OFF_XB);
  float* sq      = (float*)(ws + OFF_SQ);
  float* colpart = (float*)(ws + OFF_CP);
  float* sqpart  = (float*)(ws + OFF_SP);
  float* cf      = (float*)(ws + OFF_CF);
  float* part    = (float*)(ws + OFF_PT);

  prep_kernel<<<PREPB, 256, 0, stream>>>(src, tgt, xb, sq, colpart, sqpart);
  bw_kernel<<<1, 256, 0, stream>>>(colpart, sqpart, cf);
  pair_kernel<<<NTRI, 256, 0, stream>>>(xb, sq, cf, part);
  out_kernel<<<1, 256, 0, stream>>>(part, (float*)d_out);
}